// Round 15
// baseline (89.501 us; speedup 1.0000x reference)
//
#include <hip/hip_runtime.h>
#include <stdint.h>
#include <float.h>
#include <math.h>

// Problem constants (b_n=2, f_num=4, N=50, C_in=256, C=64, h=200, w=336)
#define HW_TOT 67200   // h*w = 384 * 175
#define NBF 8          // n = b_n*f_num
#define CO 64          // C
#define CI 256         // C_in
#define NN 50          // N
#define KK 200         // K = N*f_num
#define BN 2           // b_n
#define PT 384         // pixels per block (exact: 67200/384 = 175)
#define WAVES 6        // 384 threads

// ---------------------------------------------------------------------------
// Threefry-2x32, 20 rounds (JAX partitionable threefry semantics) — verified R1
// ---------------------------------------------------------------------------
__device__ __forceinline__ uint32_t rotl32(uint32_t v, int n) {
  return (v << n) | (v >> (32 - n));
}

__device__ void tf2x32(uint32_t k0, uint32_t k1, uint32_t x0, uint32_t x1,
                       uint32_t& o0, uint32_t& o1) {
  const uint32_t ks2 = k0 ^ k1 ^ 0x1BD11BDAu;
  x0 += k0; x1 += k1;
  x0 += x1; x1 = rotl32(x1, 13); x1 ^= x0;
  x0 += x1; x1 = rotl32(x1, 15); x1 ^= x0;
  x0 += x1; x1 = rotl32(x1, 26); x1 ^= x0;
  x0 += x1; x1 = rotl32(x1, 6);  x1 ^= x0;
  x0 += k1; x1 += ks2 + 1u;
  x0 += x1; x1 = rotl32(x1, 17); x1 ^= x0;
  x0 += x1; x1 = rotl32(x1, 29); x1 ^= x0;
  x0 += x1; x1 = rotl32(x1, 16); x1 ^= x0;
  x0 += x1; x1 = rotl32(x1, 24); x1 ^= x0;
  x0 += ks2; x1 += k0 + 2u;
  x0 += x1; x1 = rotl32(x1, 13); x1 ^= x0;
  x0 += x1; x1 = rotl32(x1, 15); x1 ^= x0;
  x0 += x1; x1 = rotl32(x1, 26); x1 ^= x0;
  x0 += x1; x1 = rotl32(x1, 6);  x1 ^= x0;
  x0 += k0; x1 += k1 + 3u;
  x0 += x1; x1 = rotl32(x1, 17); x1 ^= x0;
  x0 += x1; x1 = rotl32(x1, 29); x1 ^= x0;
  x0 += x1; x1 = rotl32(x1, 16); x1 ^= x0;
  x0 += x1; x1 = rotl32(x1, 24); x1 ^= x0;
  x0 += k1; x1 += ks2 + 4u;
  x0 += x1; x1 = rotl32(x1, 13); x1 ^= x0;
  x0 += x1; x1 = rotl32(x1, 15); x1 ^= x0;
  x0 += x1; x1 = rotl32(x1, 26); x1 ^= x0;
  x0 += x1; x1 = rotl32(x1, 6);  x1 ^= x0;
  o0 = x0 + ks2;
  o1 = x1 + k0 + 5u;
}

__device__ int jax_r(int b, int k) {
  uint32_t k1a, k1b, k2a, k2b, h0, h1, l0, l1;
  tf2x32(0u, 42u, 0u, 0u, k1a, k1b);  // split: subkey 0
  tf2x32(0u, 42u, 0u, 1u, k2a, k2b);  // split: subkey 1
  const uint32_t idx = (uint32_t)(b * KK + k);
  tf2x32(k1a, k1b, 0u, idx, h0, h1);
  tf2x32(k2a, k2b, 0u, idx, l0, l1);
  const uint32_t hb = h0 ^ h1, lb = l0 ^ l1;
  return (int)(((hb % 3u) + (lb % 3u)) % 3u);
}

// ---------------------------------------------------------------------------
// Kernel 1: mw[b][d][n] = bias[d] + sum_ci idx_feat[b][ci][n] * weight[d][ci]
// ---------------------------------------------------------------------------
__global__ __launch_bounds__(256) void k_mw(const float* __restrict__ idx_feat,
                                            const float* __restrict__ weight,
                                            const float* __restrict__ bias,
                                            float* __restrict__ mw) {
  const int tid = blockIdx.x * 256 + threadIdx.x;
  if (tid >= NBF * CO * NN) return;
  const int n = tid % NN;
  const int rest = tid / NN;
  const int d = rest % CO;
  const int b = rest / CO;
  float acc = bias[d];
  const float* feat = idx_feat + (size_t)(b * CI) * NN + n;  // stride NN per ci
  const float* wrow = weight + d * CI;
  #pragma unroll 8
  for (int ci = 0; ci < CI; ++ci)
    acc = fmaf(feat[ci * NN], wrow[ci], acc);
  mw[tid] = acc;  // layout [b][d][n]
}

// ---------------------------------------------------------------------------
// Kernel 2: contrastive loss partials. 16 blocks = 2 b * 8 chunks of 25 k.
// ---------------------------------------------------------------------------
__device__ __forceinline__ float waveMax(float v) {
  #pragma unroll
  for (int o = 32; o > 0; o >>= 1) v = fmaxf(v, __shfl_down(v, o));
  return v;
}
__device__ __forceinline__ float waveSum(float v) {
  #pragma unroll
  for (int o = 32; o > 0; o >>= 1) v += __shfl_down(v, o);
  return v;
}

__global__ __launch_bounds__(256) void k_loss(const float* __restrict__ mw,
                                              float* __restrict__ partial) {
  __shared__ __align__(16) float m_lds[KK][68];  // padded rows (54.4 KB)
  __shared__ float red[8];
  __shared__ float pos_sh;
  __shared__ int rvals[32];

  const int b = blockIdx.x >> 3;
  const int chunk = blockIdx.x & 7;
  const int t = threadIdx.x;
  const int wid = t >> 6, lane = t & 63;
  const int kbase = chunk * 25;

  if (t < 25) rvals[t] = jax_r(b, kbase + t);

  float row[CO];
  if (t < KK) {
    const int f = t & 3, ni = t >> 2;
    const float* src = mw + (size_t)((b * 4 + f) * CO) * NN + ni;  // stride NN per c
    float ssq = 0.f;
    #pragma unroll
    for (int c = 0; c < CO; ++c) { const float v = src[c * NN]; row[c] = v; ssq += v * v; }
    const float inv = 1.0f / fmaxf(sqrtf(ssq), 1e-12f);
    #pragma unroll
    for (int c = 0; c < CO; ++c) { row[c] *= inv; m_lds[t][c] = row[c]; }
  }
  __syncthreads();

  float part = 0.f;
  for (int kk = 0; kk < 25; ++kk) {
    const int k = kbase + kk;
    const int g = k >> 2, fo = k & 3;
    const int r = rvals[kk];
    const int pos_off = (r >= fo) ? r + 1 : r;
    const int pos_col = (g << 2) + pos_off;
    const int last_neg = (g == NN - 1) ? (KK - 5) : (KK - 1);  // 195 or 199

    float dot = 0.f;
    if (t < KK) {
      const float4* mk = reinterpret_cast<const float4*>(&m_lds[k][0]);  // broadcast
      #pragma unroll
      for (int c4 = 0; c4 < 16; ++c4) {
        const float4 a = mk[c4];
        dot = fmaf(a.x, row[4 * c4 + 0], dot);
        dot = fmaf(a.y, row[4 * c4 + 1], dot);
        dot = fmaf(a.z, row[4 * c4 + 2], dot);
        dot = fmaf(a.w, row[4 * c4 + 3], dot);
      }
    }
    const float logit = dot * (1.0f / 0.07f);

    float wgt = 0.f;
    if (t < KK) {
      if (t == pos_col) wgt = 1.f;
      else if ((t >> 2) != g) wgt = (t == last_neg) ? 4.f : 1.f;
    }
    const bool valid = wgt > 0.f;

    const float wmax = waveMax(valid ? logit : -FLT_MAX);
    if (lane == 0) red[wid] = wmax;
    if (t == pos_col) pos_sh = logit;
    __syncthreads();
    const float mx = fmaxf(fmaxf(red[0], red[1]), fmaxf(red[2], red[3]));
    const float pos = pos_sh;
    const float ws = waveSum(valid ? wgt * expf(logit - mx) : 0.f);
    if (lane == 0) red[4 + wid] = ws;
    __syncthreads();
    if (t == 0) {
      const float s = red[4] + red[5] + red[6] + red[7];
      part += (mx + logf(s)) - pos;
    }
    __syncthreads();
  }
  if (t == 0) partial[blockIdx.x] = part;
}

// ---------------------------------------------------------------------------
// Kernel 3 (MFMA v6): BOTH HBM STREAMS AT >=1.5 KB PER ROW-VISIT.
//  - reads: thread u loads x[c][pbase+u]; each c-row = ONE block-wide 1.5 KB
//    contiguous instruction (R11 fixed reads only; confounded)
//  - writes: acc -> LDS [25][385] f32, then 25 block-wide 1.5 KB contiguous
//    NT row-stores (R13 fixed writes only)
//  - MFMA core + LDS layouts are R14's (measured: 0 bank conflicts)
// Tests the combined read+write DRAM page-granularity theory cleanly.
// ---------------------------------------------------------------------------
typedef __attribute__((ext_vector_type(8))) short bf16x8;
typedef __attribute__((ext_vector_type(4))) float f32x4;

__device__ __forceinline__ uint32_t bf16rne(float f) {
  uint32_t u = __builtin_bit_cast(uint32_t, f);
  return (u + 0x7FFFu + ((u >> 16) & 1u)) >> 16;
}

__global__ __launch_bounds__(PT, 4) void k_pred(const float* __restrict__ x,
                                                const float* __restrict__ mw,
                                                const float* __restrict__ partial,
                                                float* __restrict__ out) {
  // input phase: [px=PT][c=64] bf16, row stride 136 B  (52,224 B)
  // output phase (aliased): [25][385] f32               (38,500 B)
  __shared__ __align__(16) char lds[PT * 136];

  const int b = blockIdx.y;
  const int pbase = blockIdx.x * PT;
  const int u = threadIdx.x;          // 0..383
  const int l = u & 63;
  const int w = u >> 6;               // wave 0..5 -> px base 64*w
  const int ln = l & 15, lg = l >> 4;

  const float* xb  = x  + (size_t)b * CO * HW_TOT + pbase;
  const float* mwb = mw + (size_t)b * CO * NN;

  // ---- A-fragments: mw gather (L1/L2-hot), R14-verified mapping ----
  bf16x8 afr[4][2];
  #pragma unroll
  for (int ns = 0; ns < 4; ++ns) {
    const int n = min(ns * 16 + ln, NN - 1);   // rows >=50 dup row 49, masked at store
    #pragma unroll
    for (int ks = 0; ks < 2; ++ks)
      #pragma unroll
      for (int j = 0; j < 8; ++j)
        afr[ns][ks][j] = (short)bf16rne(mwb[(ks * 32 + lg * 8 + j) * NN + n]);
  }

  // ---- stage: 64 c-rows, each ONE block-wide 1.5 KB contiguous read ----
  #pragma unroll
  for (int g = 0; g < 4; ++g) {
    float xr[16];
    #pragma unroll
    for (int j = 0; j < 16; ++j)
      xr[j] = xb[(size_t)(g * 16 + j) * HW_TOT + u];
    #pragma unroll
    for (int j = 0; j < 16; j += 2) {
      const uint32_t pk = bf16rne(xr[j]) | (bf16rne(xr[j + 1]) << 16);
      *reinterpret_cast<uint32_t*>(lds + u * 136 + (g * 16 + j) * 2) = pk;
    }
  }
  __syncthreads();

  // ---- MFMA: 2 k-steps x 4 p-subtiles x 4 n-subtiles (R14 mapping) ----
  f32x4 acc[4][4];
  #pragma unroll
  for (int ns = 0; ns < 4; ++ns)
    #pragma unroll
    for (int q = 0; q < 4; ++q) acc[ns][q] = (f32x4){0.f, 0.f, 0.f, 0.f};

  #pragma unroll
  for (int ks = 0; ks < 2; ++ks) {
    #pragma unroll
    for (int q = 0; q < 4; ++q) {
      const bf16x8 bfr = *reinterpret_cast<const bf16x8*>(
          lds + (size_t)(w * 64 + q * 16 + ln) * 136 + (ks * 32 + lg * 8) * 2);
      #pragma unroll
      for (int ns = 0; ns < 4; ++ns)
        acc[ns][q] = __builtin_amdgcn_mfma_f32_16x16x32_bf16(afr[ns][ks], bfr,
                                                             acc[ns][q], 0, 0, 0);
    }
  }

  // ---- epilogue: 2 halves of 25 n-rows; 1.5 KB contiguous NT row-stores ----
  float* olds = reinterpret_cast<float*>(lds);   // [25][385] f32, pad-385
  float* ob = out + (size_t)b * NN * HW_TOT + pbase;

  #pragma unroll
  for (int half = 0; half < 2; ++half) {
    __syncthreads();  // input reads (h0) / prev-half row reads (h1) done

    #pragma unroll
    for (int ns = 0; ns < 4; ++ns)
      #pragma unroll
      for (int i = 0; i < 4; ++i) {
        const int n = ns * 16 + 4 * lg + i;
        const int r = n - half * 25;
        if (r >= 0 && r < 25 && n < NN) {
          #pragma unroll
          for (int q = 0; q < 4; ++q)
            olds[r * 385 + w * 64 + q * 16 + ln] = acc[ns][q][i];
        }
      }
    __syncthreads();  // olds half complete

    #pragma unroll
    for (int r = 0; r < 25; ++r) {
      const int n = half * 25 + r;
      if (n < NN)
        __builtin_nontemporal_store(olds[r * 385 + u], ob + (size_t)n * HW_TOT + u);
    }
  }

  // Loss finalize.
  if (blockIdx.x == 0 && b == 0 && u == 0) {
    float s = 0.f;
    #pragma unroll
    for (int i = 0; i < 16; ++i) s += partial[i];
    out[(size_t)NBF * NN * HW_TOT] = s * (1.0f / KK);  // sum_b mean_k
  }
}

// ---------------------------------------------------------------------------
extern "C" void kernel_launch(void* const* d_in, const int* in_sizes, int n_in,
                              void* d_out, int out_size, void* d_ws, size_t ws_size,
                              hipStream_t stream) {
  const float* x        = (const float*)d_in[0];
  const float* idx_feat = (const float*)d_in[1];
  const float* weight   = (const float*)d_in[2];
  const float* bias     = (const float*)d_in[3];
  float* out = (float*)d_out;

  float* mw = (float*)d_ws;                 // 25600 floats
  float* partial = mw + NBF * CO * NN;      // 16 floats

  hipLaunchKernelGGL(k_mw, dim3((NBF * CO * NN + 255) / 256), dim3(256), 0, stream,
                     idx_feat, weight, bias, mw);
  hipLaunchKernelGGL(k_loss, dim3(16), dim3(256), 0, stream, mw, partial);
  hipLaunchKernelGGL(k_pred, dim3(HW_TOT / PT, NBF), dim3(PT), 0, stream,
                     x, mw, partial, out);
}